// Round 3
// baseline (1496.929 us; speedup 1.0000x reference)
//
#include <hip/hip_runtime.h>
#include <math.h>

typedef __bf16 bf16_t;
typedef bf16_t bf16x8 __attribute__((ext_vector_type(8)));
typedef bf16_t bf16x2 __attribute__((ext_vector_type(2)));
typedef float f32x4 __attribute__((ext_vector_type(4)));

#define EMBED 2048
#define NHEADS 32
#define HDIM 64
#define MLP 8192
#define SEQ 1024
#define NTOK 2048      // B*S
#define QKV_N 6144

// async global->LDS, 16B per lane; LDS dest = wave-uniform base + lane*16
__device__ __forceinline__ void async_copy16(void* lds, const void* g) {
    __builtin_amdgcn_global_load_lds(
        (const __attribute__((address_space(1))) unsigned int*)g,
        (__attribute__((address_space(3))) unsigned int*)lds, 16, 0, 0);
}

// ---------------------------------------------------------------------------
// C = A(MxK,bf16) @ Bt(NxK,bf16)^T
// EPI=0: bf16 store
// EPI=1: fp32 store, acc + Res
// EPI=2: bf16 store, silu(Aux) * acc   (Aux bf16, same layout as C)
// 128x128 tile, BK=32, 4 waves, 16x16x32 bf16 MFMA (m97 structure)
// ---------------------------------------------------------------------------
template<int EPI>
__global__ __launch_bounds__(256) void gemm_bt(
    const bf16_t* __restrict__ A, const bf16_t* __restrict__ Bt,
    void* __restrict__ Cout, const float* __restrict__ Res,
    const bf16_t* __restrict__ Aux,
    int M, int N, int K)
{
    __shared__ __align__(16) bf16_t As[128 * 32];
    __shared__ __align__(16) bf16_t Bs[128 * 32];
    const int tid = threadIdx.x;
    const int wave = tid >> 6, lane = tid & 63;
    const int quad = lane >> 4, l15 = lane & 15;
    const int wr = wave >> 1, wc = wave & 1;
    const int m0 = blockIdx.x * 128, n0 = blockIdx.y * 128;
    const int srow = lane >> 2;            // 0..15 (row within 16-row chunk)
    const int scol = (lane & 3) * 8;       // elem offset within row

    f32x4 acc[4][4] = {};

    for (int k0 = 0; k0 < K; k0 += 32) {
        if (k0) __syncthreads();
#pragma unroll
        for (int s = 0; s < 2; ++s) {
            const int chunk = wave * 2 + s;          // 0..7, 16 rows each
            const int row = chunk * 16 + srow;
            async_copy16((char*)As + chunk * 1024,
                         A + (size_t)(m0 + row) * K + k0 + scol);
            async_copy16((char*)Bs + chunk * 1024,
                         Bt + (size_t)(n0 + row) * K + k0 + scol);
        }
        asm volatile("s_waitcnt vmcnt(0)" ::: "memory");
        __syncthreads();

        bf16x8 af[4], bfr[4];
#pragma unroll
        for (int i = 0; i < 4; ++i) {
            af[i]  = *(const bf16x8*)((const char*)As + (wr * 64 + i * 16 + l15) * 64 + quad * 16);
            bfr[i] = *(const bf16x8*)((const char*)Bs + (wc * 64 + i * 16 + l15) * 64 + quad * 16);
        }
#pragma unroll
        for (int i = 0; i < 4; ++i)
#pragma unroll
            for (int j = 0; j < 4; ++j)
                acc[i][j] = __builtin_amdgcn_mfma_f32_16x16x32_bf16(af[i], bfr[j], acc[i][j], 0, 0, 0);
    }

#pragma unroll
    for (int i = 0; i < 4; ++i) {
#pragma unroll
        for (int j = 0; j < 4; ++j) {
#pragma unroll
            for (int r = 0; r < 4; ++r) {
                const int row = m0 + wr * 64 + i * 16 + quad * 4 + r;
                const int col = n0 + wc * 64 + j * 16 + l15;
                const size_t idx = (size_t)row * N + col;
                if (EPI == 0) {
                    ((bf16_t*)Cout)[idx] = (bf16_t)acc[i][j][r];
                } else if (EPI == 1) {
                    ((float*)Cout)[idx] = Res[idx] + acc[i][j][r];
                } else {
                    const float g = (float)Aux[idx];
                    const float s = g / (1.0f + __expf(-g));
                    ((bf16_t*)Cout)[idx] = (bf16_t)(s * acc[i][j][r]);
                }
            }
        }
    }
}

// ---------------------------------------------------------------------------
// W (KxN fp32) -> Wt (NxK bf16), 32x32 LDS tiles
// ---------------------------------------------------------------------------
__global__ __launch_bounds__(256) void transpose_cvt(
    const float* __restrict__ src, bf16_t* __restrict__ dst, int K, int N)
{
    __shared__ float tile[32][33];
    const int tx = threadIdx.x & 31, ty = threadIdx.x >> 5;
    const int n0 = blockIdx.x * 32, k0 = blockIdx.y * 32;
#pragma unroll
    for (int i = 0; i < 4; ++i)
        tile[ty + 8 * i][tx] = src[(size_t)(k0 + ty + 8 * i) * N + n0 + tx];
    __syncthreads();
#pragma unroll
    for (int i = 0; i < 4; ++i)
        dst[(size_t)(n0 + ty + 8 * i) * K + k0 + tx] = (bf16_t)tile[tx][ty + 8 * i];
}

// ---------------------------------------------------------------------------
// RMSNorm: fp32 row (2048) -> bf16 row
// ---------------------------------------------------------------------------
__global__ __launch_bounds__(256) void rmsnorm_bf16(
    const float* __restrict__ x, const float* __restrict__ g, bf16_t* __restrict__ out)
{
    const int row = blockIdx.x;
    const int tid = threadIdx.x;
    const float* xr = x + (size_t)row * EMBED + tid * 8;
    const float4 a = *(const float4*)xr;
    const float4 b = *(const float4*)(xr + 4);
    float ss = a.x * a.x + a.y * a.y + a.z * a.z + a.w * a.w
             + b.x * b.x + b.y * b.y + b.z * b.z + b.w * b.w;
#pragma unroll
    for (int off = 1; off < 64; off <<= 1) ss += __shfl_xor(ss, off);
    __shared__ float red[4];
    if ((tid & 63) == 0) red[tid >> 6] = ss;
    __syncthreads();
    const float rs = rsqrtf((red[0] + red[1] + red[2] + red[3]) * (1.0f / EMBED) + 1e-5f);
    const float* gr = g + tid * 8;
    const float xv[8] = {a.x, a.y, a.z, a.w, b.x, b.y, b.z, b.w};
    bf16x8 o;
#pragma unroll
    for (int e = 0; e < 8; ++e) o[e] = (bf16_t)(xv[e] * rs * gr[e]);
    *(bf16x8*)(out + (size_t)row * EMBED + tid * 8) = o;
}

// ---------------------------------------------------------------------------
// qkv [tok][6144] -> head-major Qh,Kh,Vh [(b*32+h)][s][64], RoPE on q,k.
// One thread per (token, head).
// ---------------------------------------------------------------------------
__global__ __launch_bounds__(256) void rope_transpose(
    const bf16_t* __restrict__ qkv, bf16_t* __restrict__ Qh,
    bf16_t* __restrict__ Kh, bf16_t* __restrict__ Vh)
{
    const int id = blockIdx.x * 256 + threadIdx.x;   // 0..65535
    const int tok = id >> 5;
    const int h = id & 31;
    const int s = tok & (SEQ - 1);
    const int bh = (tok >> 10) * NHEADS + h;
    const size_t dst = ((size_t)bh * SEQ + s) * HDIM;

    const bf16_t* q = qkv + (size_t)tok * QKV_N + h * HDIM;
    const bf16_t* k = q + EMBED;
    const bf16_t* v = q + 2 * EMBED;

    // V: straight copy, 64 elems = 8x bf16x8
#pragma unroll
    for (int c = 0; c < 8; ++c)
        ((bf16x8*)(Vh + dst))[c] = ((const bf16x8*)v)[c];

    // Q,K: rope on pairs (2i, 2i+1)
    const bf16x2* qp = (const bf16x2*)q;
    const bf16x2* kp = (const bf16x2*)k;
    bf16x2* qo = (bf16x2*)(Qh + dst);
    bf16x2* ko = (bf16x2*)(Kh + dst);
    for (int i = 0; i < 32; ++i) {
        const float inv = 1.0f / powf(500000.0f, (float)i * (1.0f / 32.0f));
        const float ang = (float)s * inv;
        float sn, cs;
        sincosf(ang, &sn, &cs);
        bf16x2 qv = qp[i], kv = kp[i];
        const float q0 = (float)qv[0], q1 = (float)qv[1];
        const float k0 = (float)kv[0], k1 = (float)kv[1];
        qv[0] = (bf16_t)(q0 * cs - q1 * sn); qv[1] = (bf16_t)(q0 * sn + q1 * cs);
        kv[0] = (bf16_t)(k0 * cs - k1 * sn); kv[1] = (bf16_t)(k0 * sn + k1 * cs);
        qo[i] = qv; ko[i] = kv;
    }
}

// ---------------------------------------------------------------------------
// Tile-sparse attention v2. Block = (qtile, head, batch), 4 waves.
// Pass1: waves split key tiles (t = wave mod 4) -> tile maxima in LDS.
// Select top-12 tiles/query (+own) on wave 0.
// Pass2: per-wave online softmax over its selected tiles (wave-local LDS,
// no barriers), then flash-decode merge of 4 wave partials on wave 0.
// ---------------------------------------------------------------------------
__global__ __launch_bounds__(256) void attn_sparse(
    const bf16_t* __restrict__ Qh, const bf16_t* __restrict__ Kh,
    const bf16_t* __restrict__ Vh, bf16_t* __restrict__ attn)
{
    const int qt = 63 - blockIdx.x;  // long blocks first
    const int h  = blockIdx.y;
    const int b  = blockIdx.z;
    const int tid  = threadIdx.x;
    const int wave = tid >> 6, lane = tid & 63;
    const int quad = lane >> 4, l15 = lane & 15;

    __shared__ float tilemax[16][66];
    __shared__ unsigned long long qmask[16];
    __shared__ float Vlds[4][16][68];
    __shared__ float Plds[4][16][17];
    __shared__ float Alds[4][16];
    __shared__ float Ow[4][16][64];
    __shared__ float Ml[4][16];
    __shared__ float Ll[4][16];

    const size_t hoff = (size_t)(b * NHEADS + h) * SEQ * HDIM;
    const bf16_t* Qb = Qh + hoff;
    const bf16_t* Kb = Kh + hoff;
    const bf16_t* Vb = Vh + hoff;

    const bf16_t* qrow = Qb + (size_t)(qt * 16 + l15) * HDIM;
    const bf16x8 qf0 = *(const bf16x8*)(qrow + quad * 8);
    const bf16x8 qf1 = *(const bf16x8*)(qrow + 32 + quad * 8);

    // ---- pass 1: tile maxima (waves split t-range) ----
    for (int t = wave; t <= qt; t += 4) {
        const bf16_t* krow = Kb + (size_t)(t * 16 + l15) * HDIM;
        const bf16x8 kf0 = *(const bf16x8*)(krow + quad * 8);
        const bf16x8 kf1 = *(const bf16x8*)(krow + 32 + quad * 8);
        f32x4 sc = {0.f, 0.f, 0.f, 0.f};
        sc = __builtin_amdgcn_mfma_f32_16x16x32_bf16(qf0, kf0, sc, 0, 0, 0);
        sc = __builtin_amdgcn_mfma_f32_16x16x32_bf16(qf1, kf1, sc, 0, 0, 0);
#pragma unroll
        for (int r = 0; r < 4; ++r) {
            const int qr = quad * 4 + r;
            float v = sc[r] * 0.125f;
            if (t == qt && l15 > qr) v = -3.0e38f;   // causal within own tile
            v = fmaxf(v, __shfl_xor(v, 1));
            v = fmaxf(v, __shfl_xor(v, 2));
            v = fmaxf(v, __shfl_xor(v, 4));
            v = fmaxf(v, __shfl_xor(v, 8));
            if (l15 == 0) tilemax[qr][t] = v;
        }
    }
    __syncthreads();

    // ---- selection: top-12 (strict >, earliest on ties) + own ----
    if (tid < 16) {
        unsigned long long m = 0;
        const int cnt = qt + 1;
        if (cnt <= 12) {
            m = (1ull << cnt) - 1ull;
        } else {
            for (int it = 0; it < 12; ++it) {
                float best = -3.9e38f; int bi = 0;
                for (int t = 0; t <= qt; ++t) {
                    if ((m >> t) & 1ull) continue;
                    const float v = tilemax[tid][t];
                    if (v > best) { best = v; bi = t; }
                }
                m |= 1ull << bi;
            }
        }
        m |= 1ull << qt;
        qmask[tid] = m;
    }
    __syncthreads();

    unsigned long long un = 0;
#pragma unroll
    for (int i = 0; i < 16; ++i) un |= qmask[i];
    unsigned long long myrow[4];
#pragma unroll
    for (int r = 0; r < 4; ++r) myrow[r] = qmask[quad * 4 + r];

    float m_run[4], l_run[4];
#pragma unroll
    for (int r = 0; r < 4; ++r) { m_run[r] = -3.0e38f; l_run[r] = 0.f; }
    float o[16];
#pragma unroll
    for (int e = 0; e < 16; ++e) o[e] = 0.f;

    // ---- pass 2: per-wave online softmax + PV, no cross-wave syncs ----
    for (int t = wave; t <= qt; t += 4) {
        if (!((un >> t) & 1ull)) continue;
        {   // stage V tile (fp32) into this wave's LDS slab
            const bf16_t* vb = Vb + (size_t)(t * 16 + l15) * HDIM + quad * 16;
            const bf16x8 v0 = *(const bf16x8*)vb;
            const bf16x8 v1 = *(const bf16x8*)(vb + 8);
#pragma unroll
            for (int e = 0; e < 8; ++e) {
                Vlds[wave][l15][quad * 16 + e]     = (float)v0[e];
                Vlds[wave][l15][quad * 16 + 8 + e] = (float)v1[e];
            }
        }
        const bf16_t* krow = Kb + (size_t)(t * 16 + l15) * HDIM;
        const bf16x8 kf0 = *(const bf16x8*)(krow + quad * 8);
        const bf16x8 kf1 = *(const bf16x8*)(krow + 32 + quad * 8);
        f32x4 sc = {0.f, 0.f, 0.f, 0.f};
        sc = __builtin_amdgcn_mfma_f32_16x16x32_bf16(qf0, kf0, sc, 0, 0, 0);
        sc = __builtin_amdgcn_mfma_f32_16x16x32_bf16(qf1, kf1, sc, 0, 0, 0);
#pragma unroll
        for (int r = 0; r < 4; ++r) {
            const int qr = quad * 4 + r;
            const bool ok = ((myrow[r] >> t) & 1ull) && (t < qt || l15 <= qr);
            const float sv = ok ? sc[r] * 0.125f : -3.0e38f;
            float mt = sv;
            mt = fmaxf(mt, __shfl_xor(mt, 1));
            mt = fmaxf(mt, __shfl_xor(mt, 2));
            mt = fmaxf(mt, __shfl_xor(mt, 4));
            mt = fmaxf(mt, __shfl_xor(mt, 8));
            const float mn = fmaxf(m_run[r], mt);
            const float al = __expf(m_run[r] - mn);
            const float pv = ok ? __expf(sv - mn) : 0.f;
            float rsum = pv;
            rsum += __shfl_xor(rsum, 1);
            rsum += __shfl_xor(rsum, 2);
            rsum += __shfl_xor(rsum, 4);
            rsum += __shfl_xor(rsum, 8);
            l_run[r] = l_run[r] * al + rsum;
            m_run[r] = mn;
            Plds[wave][qr][l15] = pv;
            if (l15 == 0) Alds[wave][qr] = al;
        }
        // in-wave LDS ordering: DS ops complete in order; drain before reads
        asm volatile("s_waitcnt lgkmcnt(0)" ::: "memory");
        const float aq = Alds[wave][l15];
#pragma unroll
        for (int e = 0; e < 16; ++e) o[e] *= aq;
#pragma unroll
        for (int k = 0; k < 16; ++k) {
            const float pk = Plds[wave][l15][k];
            const float4* vr = (const float4*)&Vlds[wave][k][quad * 16];
            const float4 va = vr[0], vb2 = vr[1], vc2 = vr[2], vd = vr[3];
            o[0]  += pk * va.x;  o[1]  += pk * va.y;  o[2]  += pk * va.z;  o[3]  += pk * va.w;
            o[4]  += pk * vb2.x; o[5]  += pk * vb2.y; o[6]  += pk * vb2.z; o[7]  += pk * vb2.w;
            o[8]  += pk * vc2.x; o[9]  += pk * vc2.y; o[10] += pk * vc2.z; o[11] += pk * vc2.w;
            o[12] += pk * vd.x;  o[13] += pk * vd.y;  o[14] += pk * vd.z;  o[15] += pk * vd.w;
        }
    }

    // ---- store wave partials, merge on wave 0 ----
    if (l15 == 0) {
#pragma unroll
        for (int r = 0; r < 4; ++r) {
            Ml[wave][quad * 4 + r] = m_run[r];
            Ll[wave][quad * 4 + r] = l_run[r];
        }
    }
#pragma unroll
    for (int e = 0; e < 16; ++e) Ow[wave][l15][quad * 16 + e] = o[e];
    __syncthreads();

    if (wave == 0) {
        const int row = l15;
        float mw[4], sw[4];
#pragma unroll
        for (int w = 0; w < 4; ++w) mw[w] = Ml[w][row];
        float mst = fmaxf(fmaxf(mw[0], mw[1]), fmaxf(mw[2], mw[3]));
        float lsum = 0.f;
#pragma unroll
        for (int w = 0; w < 4; ++w) {
            sw[w] = __expf(mw[w] - mst);
            lsum += Ll[w][row] * sw[w];
        }
        const float inv = 1.0f / lsum;
        bf16x8 o0, o1;
#pragma unroll
        for (int e = 0; e < 16; ++e) {
            float acc = 0.f;
#pragma unroll
            for (int w = 0; w < 4; ++w) acc += Ow[w][row][quad * 16 + e] * sw[w];
            const float res = acc * inv;
            if (e < 8) o0[e] = (bf16_t)res; else o1[e - 8] = (bf16_t)res;
        }
        bf16_t* op = attn + (size_t)(b * SEQ + qt * 16 + row) * EMBED + h * HDIM + quad * 16;
        *(bf16x8*)op = o0;
        *(bf16x8*)(op + 8) = o1;
    }
}

// ---------------------------------------------------------------------------
// silu(gate) * up fused into up-GEMM epilogue (EPI=2). No standalone kernel.
//
// Workspace layout (120 MB peak, lifetime-overlaid):
//   [0,32M)     Wt region: wqkv_t(24M) / wo_t(8M) / wg_t(32M) / wu_t(32M) / wd_t(32M)
//   [32,56M)    qkv(24M)          -> later gate(32M) spans [32,64M)
//   [56,64M)    attnb(8M)
//   [64,80M)    x1 fp32(16M)
//   [80,88M)    nbuf/n2(8M)
//   [88,118M)   Qh/Kh/Vh(3x~10M)  -> later hbuf(32M) spans [88,120M)
// ---------------------------------------------------------------------------
extern "C" void kernel_launch(void* const* d_in, const int* in_sizes, int n_in,
                              void* d_out, int out_size, void* d_ws, size_t ws_size,
                              hipStream_t stream)
{
    const float* x   = (const float*)d_in[0];
    const float* ans = (const float*)d_in[1];
    const float* wq  = (const float*)d_in[2];
    const float* wk  = (const float*)d_in[3];
    const float* wv  = (const float*)d_in[4];
    const float* wo  = (const float*)d_in[5];
    const float* fns = (const float*)d_in[6];
    const float* wg  = (const float*)d_in[7];
    const float* wu  = (const float*)d_in[8];
    const float* wd  = (const float*)d_in[9];
    (void)in_sizes; (void)n_in; (void)out_size; (void)ws_size;

    char* ws = (char*)d_ws;
    const size_t MB = 1024 * 1024;
    bf16_t* wt_reg = (bf16_t*)(ws);             // 32 MB weight region
    bf16_t* qkv    = (bf16_t*)(ws + 32 * MB);   // 24 MB
    bf16_t* attnb  = (bf16_t*)(ws + 56 * MB);   // 8 MB
    bf16_t* gate   = (bf16_t*)(ws + 32 * MB);   // 32 MB (overlays dead qkv+attnb)
    float*  x1     = (float* )(ws + 64 * MB);   // 16 MB
    bf16_t* nbuf   = (bf16_t*)(ws + 80 * MB);   // 8 MB (also n2)
    bf16_t* Qh     = (bf16_t*)(ws + 88 * MB);   // 8.4 MB
    bf16_t* Kh     = (bf16_t*)(ws + 98 * MB);   // 8.4 MB
    bf16_t* Vh     = (bf16_t*)(ws + 108 * MB);  // 8.4 MB
    bf16_t* hbuf   = (bf16_t*)(ws + 88 * MB);   // 32 MB (overlays dead Qh/Kh/Vh)

    // ---- attention phase ----
    transpose_cvt<<<dim3(64, 64), 256, 0, stream>>>(wq, wt_reg,                             EMBED, EMBED);
    transpose_cvt<<<dim3(64, 64), 256, 0, stream>>>(wk, wt_reg + (size_t)EMBED * EMBED,     EMBED, EMBED);
    transpose_cvt<<<dim3(64, 64), 256, 0, stream>>>(wv, wt_reg + (size_t)2 * EMBED * EMBED, EMBED, EMBED);
    rmsnorm_bf16<<<NTOK, 256, 0, stream>>>(x, ans, nbuf);
    gemm_bt<0><<<dim3(16, 48), 256, 0, stream>>>(nbuf, wt_reg, qkv, nullptr, nullptr, NTOK, QKV_N, EMBED);
    rope_transpose<<<256, 256, 0, stream>>>(qkv, Qh, Kh, Vh);
    attn_sparse<<<dim3(64, 32, 2), 256, 0, stream>>>(Qh, Kh, Vh, attnb);
    transpose_cvt<<<dim3(64, 64), 256, 0, stream>>>(wo, wt_reg, EMBED, EMBED);   // wqkv_t dead
    gemm_bt<1><<<dim3(16, 16), 256, 0, stream>>>(attnb, wt_reg, x1, x, nullptr, NTOK, EMBED, EMBED);

    // ---- MLP phase ----
    rmsnorm_bf16<<<NTOK, 256, 0, stream>>>(x1, fns, nbuf);                       // n2
    transpose_cvt<<<dim3(256, 64), 256, 0, stream>>>(wg, wt_reg, EMBED, MLP);    // wo_t dead
    gemm_bt<0><<<dim3(16, 64), 256, 0, stream>>>(nbuf, wt_reg, gate, nullptr, nullptr, NTOK, MLP, EMBED);
    transpose_cvt<<<dim3(256, 64), 256, 0, stream>>>(wu, wt_reg, EMBED, MLP);    // wg_t dead
    gemm_bt<2><<<dim3(16, 64), 256, 0, stream>>>(nbuf, wt_reg, hbuf, nullptr, gate, NTOK, MLP, EMBED);
    transpose_cvt<<<dim3(64, 256), 256, 0, stream>>>(wd, wt_reg, MLP, EMBED);    // wu_t dead
    gemm_bt<1><<<dim3(16, 16), 256, 0, stream>>>(hbuf, wt_reg, (float*)d_out, x1, nullptr, NTOK, EMBED, MLP);
}

// Round 4
// 1150.415 us; speedup vs baseline: 1.3012x; 1.3012x over previous
//
#include <hip/hip_runtime.h>
#include <math.h>

typedef __bf16 bf16_t;
typedef bf16_t bf16x8 __attribute__((ext_vector_type(8)));
typedef bf16_t bf16x2 __attribute__((ext_vector_type(2)));
typedef float f32x4 __attribute__((ext_vector_type(4)));

#define EMBED 2048
#define NHEADS 32
#define HDIM 64
#define MLP 8192
#define SEQ 1024
#define NTOK 2048      // B*S
#define QKV_N 6144

// async global->LDS, 16B per lane; LDS dest = wave-uniform base + lane*16
__device__ __forceinline__ void async_copy16(void* lds, const void* g) {
    __builtin_amdgcn_global_load_lds(
        (const __attribute__((address_space(1))) unsigned int*)g,
        (__attribute__((address_space(3))) unsigned int*)lds, 16, 0, 0);
}

// ---------------------------------------------------------------------------
// C = A(MxK,bf16) @ Bt(NxK,bf16)^T
// EPI=0: bf16 store | EPI=1: fp32 store acc+Res | EPI=2: bf16 silu(Aux)*acc
// 128x128 tile, BK=32, 4 waves, 16x16x32 bf16 MFMA (m97 structure)
// ---------------------------------------------------------------------------
template<int EPI>
__global__ __launch_bounds__(256) void gemm_bt(
    const bf16_t* __restrict__ A, const bf16_t* __restrict__ Bt,
    void* __restrict__ Cout, const float* __restrict__ Res,
    const bf16_t* __restrict__ Aux,
    int M, int N, int K)
{
    __shared__ __align__(16) bf16_t As[128 * 32];
    __shared__ __align__(16) bf16_t Bs[128 * 32];
    const int tid = threadIdx.x;
    const int wave = tid >> 6, lane = tid & 63;
    const int quad = lane >> 4, l15 = lane & 15;
    const int wr = wave >> 1, wc = wave & 1;
    const int m0 = blockIdx.x * 128, n0 = blockIdx.y * 128;
    const int srow = lane >> 2;
    const int scol = (lane & 3) * 8;

    f32x4 acc[4][4] = {};

    for (int k0 = 0; k0 < K; k0 += 32) {
        if (k0) __syncthreads();
#pragma unroll
        for (int s = 0; s < 2; ++s) {
            const int chunk = wave * 2 + s;
            const int row = chunk * 16 + srow;
            async_copy16((char*)As + chunk * 1024,
                         A + (size_t)(m0 + row) * K + k0 + scol);
            async_copy16((char*)Bs + chunk * 1024,
                         Bt + (size_t)(n0 + row) * K + k0 + scol);
        }
        asm volatile("s_waitcnt vmcnt(0)" ::: "memory");
        __syncthreads();

        bf16x8 af[4], bfr[4];
#pragma unroll
        for (int i = 0; i < 4; ++i) {
            af[i]  = *(const bf16x8*)((const char*)As + (wr * 64 + i * 16 + l15) * 64 + quad * 16);
            bfr[i] = *(const bf16x8*)((const char*)Bs + (wc * 64 + i * 16 + l15) * 64 + quad * 16);
        }
#pragma unroll
        for (int i = 0; i < 4; ++i)
#pragma unroll
            for (int j = 0; j < 4; ++j)
                acc[i][j] = __builtin_amdgcn_mfma_f32_16x16x32_bf16(af[i], bfr[j], acc[i][j], 0, 0, 0);
    }

#pragma unroll
    for (int i = 0; i < 4; ++i) {
#pragma unroll
        for (int j = 0; j < 4; ++j) {
#pragma unroll
            for (int r = 0; r < 4; ++r) {
                const int row = m0 + wr * 64 + i * 16 + quad * 4 + r;
                const int col = n0 + wc * 64 + j * 16 + l15;
                const size_t idx = (size_t)row * N + col;
                if (EPI == 0) {
                    ((bf16_t*)Cout)[idx] = (bf16_t)acc[i][j][r];
                } else if (EPI == 1) {
                    ((float*)Cout)[idx] = Res[idx] + acc[i][j][r];
                } else {
                    const float g = (float)Aux[idx];
                    const float s = g / (1.0f + __expf(-g));
                    ((bf16_t*)Cout)[idx] = (bf16_t)(s * acc[i][j][r]);
                }
            }
        }
    }
}

// ---------------------------------------------------------------------------
// W (KxN fp32) -> Wt (NxK bf16), 32x32 LDS tiles
// ---------------------------------------------------------------------------
__global__ __launch_bounds__(256) void transpose_cvt(
    const float* __restrict__ src, bf16_t* __restrict__ dst, int K, int N)
{
    __shared__ float tile[32][33];
    const int tx = threadIdx.x & 31, ty = threadIdx.x >> 5;
    const int n0 = blockIdx.x * 32, k0 = blockIdx.y * 32;
#pragma unroll
    for (int i = 0; i < 4; ++i)
        tile[ty + 8 * i][tx] = src[(size_t)(k0 + ty + 8 * i) * N + n0 + tx];
    __syncthreads();
#pragma unroll
    for (int i = 0; i < 4; ++i)
        dst[(size_t)(n0 + ty + 8 * i) * K + k0 + tx] = (bf16_t)tile[tx][ty + 8 * i];
}

// ---------------------------------------------------------------------------
// RMSNorm: fp32 row (2048) -> bf16 row
// ---------------------------------------------------------------------------
__global__ __launch_bounds__(256) void rmsnorm_bf16(
    const float* __restrict__ x, const float* __restrict__ g, bf16_t* __restrict__ out)
{
    const int row = blockIdx.x;
    const int tid = threadIdx.x;
    const float* xr = x + (size_t)row * EMBED + tid * 8;
    const float4 a = *(const float4*)xr;
    const float4 b = *(const float4*)(xr + 4);
    float ss = a.x * a.x + a.y * a.y + a.z * a.z + a.w * a.w
             + b.x * b.x + b.y * b.y + b.z * b.z + b.w * b.w;
#pragma unroll
    for (int off = 1; off < 64; off <<= 1) ss += __shfl_xor(ss, off);
    __shared__ float red[4];
    if ((tid & 63) == 0) red[tid >> 6] = ss;
    __syncthreads();
    const float rs = rsqrtf((red[0] + red[1] + red[2] + red[3]) * (1.0f / EMBED) + 1e-5f);
    const float* gr = g + tid * 8;
    const float xv[8] = {a.x, a.y, a.z, a.w, b.x, b.y, b.z, b.w};
    bf16x8 o;
#pragma unroll
    for (int e = 0; e < 8; ++e) o[e] = (bf16_t)(xv[e] * rs * gr[e]);
    *(bf16x8*)(out + (size_t)row * EMBED + tid * 8) = o;
}

// ---------------------------------------------------------------------------
// qkv [tok][6144] -> head-major Qh,Kh,Vh [(b*32+h)][s][64], RoPE on q,k.
// ---------------------------------------------------------------------------
__global__ __launch_bounds__(256) void rope_transpose(
    const bf16_t* __restrict__ qkv, bf16_t* __restrict__ Qh,
    bf16_t* __restrict__ Kh, bf16_t* __restrict__ Vh)
{
    const int id = blockIdx.x * 256 + threadIdx.x;   // 0..65535
    const int tok = id >> 5;
    const int h = id & 31;
    const int s = tok & (SEQ - 1);
    const int bh = (tok >> 10) * NHEADS + h;
    const size_t dst = ((size_t)bh * SEQ + s) * HDIM;

    const bf16_t* q = qkv + (size_t)tok * QKV_N + h * HDIM;
    const bf16_t* k = q + EMBED;
    const bf16_t* v = q + 2 * EMBED;

#pragma unroll
    for (int c = 0; c < 8; ++c)
        ((bf16x8*)(Vh + dst))[c] = ((const bf16x8*)v)[c];

    const bf16x2* qp = (const bf16x2*)q;
    const bf16x2* kp = (const bf16x2*)k;
    bf16x2* qo = (bf16x2*)(Qh + dst);
    bf16x2* ko = (bf16x2*)(Kh + dst);
    for (int i = 0; i < 32; ++i) {
        // 1/theta^(i/32) = exp2(-i*log2(theta)/32), log2(5e5)=18.9315685693
        const float inv = exp2f((float)i * -0.59161151779f);
        const float ang = (float)s * inv;
        float sn, cs;
        sincosf(ang, &sn, &cs);
        bf16x2 qv = qp[i], kv = kp[i];
        const float q0 = (float)qv[0], q1 = (float)qv[1];
        const float k0 = (float)kv[0], k1 = (float)kv[1];
        qv[0] = (bf16_t)(q0 * cs - q1 * sn); qv[1] = (bf16_t)(q0 * sn + q1 * cs);
        kv[0] = (bf16_t)(k0 * cs - k1 * sn); kv[1] = (bf16_t)(k0 * sn + k1 * cs);
        qo[i] = qv; ko[i] = kv;
    }
}

// ---------------------------------------------------------------------------
// Tile-sparse attention v3. Block = (qgroup of 4 tiles, head, batch), 4 waves.
// Each wave owns ONE 16-query tile end-to-end: no barriers, no merge.
// Pass1: QK^T tile maxima (K frags direct from global, pipelined).
// Select top-12 (+own) per query row.
// Pass2: selected tiles in PAIRS (K=32): online softmax, P->bf16 LDS
// transpose (C->A layout), V->LDS transpose (B layout), PV via MFMA.
// ---------------------------------------------------------------------------
__global__ __launch_bounds__(256) void attn_sparse(
    const bf16_t* __restrict__ Qh, const bf16_t* __restrict__ Kh,
    const bf16_t* __restrict__ Vh, bf16_t* __restrict__ attn)
{
    const int qg = 15 - blockIdx.x;  // big blocks first
    const int h  = blockIdx.y;
    const int b  = blockIdx.z;
    const int tid  = threadIdx.x;
    const int wave = tid >> 6, lane = tid & 63;
    const int quad = lane >> 4, l15 = lane & 15;
    const int qt = qg * 4 + wave;    // this wave's query tile (0..63)

    // per-wave LDS slabs (padded to kill bank conflicts)
    __shared__ __align__(16) float  tilemax[4][16][68];
    __shared__ __align__(16) bf16_t Plds[4][16][40];
    __shared__ __align__(16) bf16_t Vt[4][64][40];
    __shared__ unsigned long long qmask[4][16];

    const size_t hoff = (size_t)(b * NHEADS + h) * SEQ * HDIM;
    const bf16_t* Qb = Qh + hoff;
    const bf16_t* Kb = Kh + hoff;
    const bf16_t* Vb = Vh + hoff;

    const bf16_t* qrow = Qb + (size_t)(qt * 16 + l15) * HDIM;
    const bf16x8 qf0 = *(const bf16x8*)(qrow + quad * 8);
    const bf16x8 qf1 = *(const bf16x8*)(qrow + 32 + quad * 8);

    // ---- pass 1: tile maxima (per-wave, pipelined K loads) ----
    bf16x8 kc0, kc1, kn0, kn1;
    {
        const bf16_t* kr = Kb + (size_t)(l15) * HDIM;
        kc0 = *(const bf16x8*)(kr + quad * 8);
        kc1 = *(const bf16x8*)(kr + 32 + quad * 8);
    }
    for (int t = 0; t <= qt; ++t) {
        const int tn = (t < qt) ? t + 1 : t;
        const bf16_t* kr = Kb + (size_t)(tn * 16 + l15) * HDIM;
        kn0 = *(const bf16x8*)(kr + quad * 8);
        kn1 = *(const bf16x8*)(kr + 32 + quad * 8);
        f32x4 sc = {0.f, 0.f, 0.f, 0.f};
        sc = __builtin_amdgcn_mfma_f32_16x16x32_bf16(qf0, kc0, sc, 0, 0, 0);
        sc = __builtin_amdgcn_mfma_f32_16x16x32_bf16(qf1, kc1, sc, 0, 0, 0);
#pragma unroll
        for (int r = 0; r < 4; ++r) {
            const int qr = quad * 4 + r;
            float v = sc[r] * 0.125f;
            if (t == qt && l15 > qr) v = -3.0e38f;
            v = fmaxf(v, __shfl_xor(v, 1));
            v = fmaxf(v, __shfl_xor(v, 2));
            v = fmaxf(v, __shfl_xor(v, 4));
            v = fmaxf(v, __shfl_xor(v, 8));
            if (l15 == 0) tilemax[wave][qr][t] = v;
        }
        kc0 = kn0; kc1 = kn1;
    }
    asm volatile("s_waitcnt lgkmcnt(0)" ::: "memory");   // in-wave DS drain

    // ---- selection: top-12 (strict >, earliest on ties) + own ----
    if (lane < 16) {
        unsigned long long m = 0;
        const int cnt = qt + 1;
        if (cnt <= 12) {
            m = (1ull << cnt) - 1ull;
        } else {
            const float* tmrow = &tilemax[wave][lane][0];
            const int c4 = qt >> 2;
            for (int it = 0; it < 12; ++it) {
                float best = -3.9e38f; int bi = 0;
                for (int c = 0; c <= c4; ++c) {
                    const float4 v4 = *(const float4*)(tmrow + c * 4);
                    const int tb = c * 4;
                    if (tb + 0 <= qt && !((m >> (tb + 0)) & 1ull) && v4.x > best) { best = v4.x; bi = tb + 0; }
                    if (tb + 1 <= qt && !((m >> (tb + 1)) & 1ull) && v4.y > best) { best = v4.y; bi = tb + 1; }
                    if (tb + 2 <= qt && !((m >> (tb + 2)) & 1ull) && v4.z > best) { best = v4.z; bi = tb + 2; }
                    if (tb + 3 <= qt && !((m >> (tb + 3)) & 1ull) && v4.w > best) { best = v4.w; bi = tb + 3; }
                }
                m |= 1ull << bi;
            }
        }
        m |= 1ull << qt;
        qmask[wave][lane] = m;
    }
    asm volatile("s_waitcnt lgkmcnt(0)" ::: "memory");

    unsigned long long un = 0;
#pragma unroll
    for (int i = 0; i < 16; ++i) un |= qmask[wave][i];
    unsigned long long myrow[4];
#pragma unroll
    for (int r = 0; r < 4; ++r) myrow[r] = qmask[wave][quad * 4 + r];

    float m_run[4], l_run[4];
#pragma unroll
    for (int r = 0; r < 4; ++r) { m_run[r] = -3.0e38f; l_run[r] = 0.f; }
    f32x4 o[4] = {};   // o[jb][r] = D[quad*4+r][jb*16+l15]

    // ---- pass 2: selected tiles in pairs, MFMA PV ----
    unsigned long long sel = un;
    while (sel) {
        const int t0 = (int)__builtin_ctzll(sel); sel &= sel - 1ull;
        int t1 = -1;
        if (sel) { t1 = (int)__builtin_ctzll(sel); sel &= sel - 1ull; }
        const int t1e = (t1 >= 0) ? t1 : t0;

        // K frags for both tiles (direct global, L2-hot)
        const bf16_t* kr0 = Kb + (size_t)(t0 * 16 + l15) * HDIM;
        const bf16x8 k00 = *(const bf16x8*)(kr0 + quad * 8);
        const bf16x8 k01 = *(const bf16x8*)(kr0 + 32 + quad * 8);
        const bf16_t* kr1 = Kb + (size_t)(t1e * 16 + l15) * HDIM;
        const bf16x8 k10 = *(const bf16x8*)(kr1 + quad * 8);
        const bf16x8 k11 = *(const bf16x8*)(kr1 + 32 + quad * 8);

        // V transpose-stage: Vt[dim][key], keys 0-15 = t0, 16-31 = t1e
        {
            const bf16_t* vr0 = Vb + (size_t)(t0 * 16 + l15) * HDIM + quad * 16;
            const bf16x8 va = *(const bf16x8*)vr0;
            const bf16x8 vb8 = *(const bf16x8*)(vr0 + 8);
            const bf16_t* vr1 = Vb + (size_t)(t1e * 16 + l15) * HDIM + quad * 16;
            const bf16x8 vc = *(const bf16x8*)vr1;
            const bf16x8 vd = *(const bf16x8*)(vr1 + 8);
#pragma unroll
            for (int e = 0; e < 8; ++e) {
                Vt[wave][quad * 16 + e][l15]          = va[e];
                Vt[wave][quad * 16 + 8 + e][l15]      = vb8[e];
                Vt[wave][quad * 16 + e][16 + l15]     = vc[e];
                Vt[wave][quad * 16 + 8 + e][16 + l15] = vd[e];
            }
        }

        f32x4 s0 = {0.f, 0.f, 0.f, 0.f}, s1 = {0.f, 0.f, 0.f, 0.f};
        s0 = __builtin_amdgcn_mfma_f32_16x16x32_bf16(qf0, k00, s0, 0, 0, 0);
        s0 = __builtin_amdgcn_mfma_f32_16x16x32_bf16(qf1, k01, s0, 0, 0, 0);
        s1 = __builtin_amdgcn_mfma_f32_16x16x32_bf16(qf0, k10, s1, 0, 0, 0);
        s1 = __builtin_amdgcn_mfma_f32_16x16x32_bf16(qf1, k11, s1, 0, 0, 0);

#pragma unroll
        for (int r = 0; r < 4; ++r) {
            const int qr = quad * 4 + r;
            const bool ok0 = ((myrow[r] >> t0) & 1ull) && (t0 < qt || l15 <= qr);
            const bool ok1 = (t1 >= 0) && ((myrow[r] >> t1) & 1ull) && (t1 < qt || l15 <= qr);
            const float sv0 = ok0 ? s0[r] * 0.125f : -3.0e38f;
            const float sv1 = ok1 ? s1[r] * 0.125f : -3.0e38f;
            float mt = fmaxf(sv0, sv1);
            mt = fmaxf(mt, __shfl_xor(mt, 1));
            mt = fmaxf(mt, __shfl_xor(mt, 2));
            mt = fmaxf(mt, __shfl_xor(mt, 4));
            mt = fmaxf(mt, __shfl_xor(mt, 8));
            const float mn = fmaxf(m_run[r], mt);
            const float al = __expf(m_run[r] - mn);
            const float p0 = ok0 ? __expf(sv0 - mn) : 0.f;
            const float p1 = ok1 ? __expf(sv1 - mn) : 0.f;
            float rsum = p0 + p1;
            rsum += __shfl_xor(rsum, 1);
            rsum += __shfl_xor(rsum, 2);
            rsum += __shfl_xor(rsum, 4);
            rsum += __shfl_xor(rsum, 8);
            l_run[r] = l_run[r] * al + rsum;
            m_run[r] = mn;
            Plds[wave][qr][l15]      = (bf16_t)p0;
            Plds[wave][qr][16 + l15] = (bf16_t)p1;
#pragma unroll
            for (int jb = 0; jb < 4; ++jb) o[jb][r] *= al;
        }
        asm volatile("s_waitcnt lgkmcnt(0)" ::: "memory");

        // A-frag: P[m=l15][k=quad*8+j]; B-frag per jb: Vt[jb*16+l15][quad*8+j]
        const bf16x8 pa = *(const bf16x8*)&Plds[wave][l15][quad * 8];
#pragma unroll
        for (int jb = 0; jb < 4; ++jb) {
            const bf16x8 vbf = *(const bf16x8*)&Vt[wave][jb * 16 + l15][quad * 8];
            o[jb] = __builtin_amdgcn_mfma_f32_16x16x32_bf16(pa, vbf, o[jb], 0, 0, 0);
        }
    }

    // ---- epilogue: normalize, store ----
    const int tok0 = b * SEQ + qt * 16;
#pragma unroll
    for (int r = 0; r < 4; ++r) {
        const int qr = quad * 4 + r;
        const float inv = 1.0f / l_run[r];
        bf16_t* op = attn + (size_t)(tok0 + qr) * EMBED + h * HDIM + l15;
#pragma unroll
        for (int jb = 0; jb < 4; ++jb)
            op[jb * 16] = (bf16_t)(o[jb][r] * inv);
    }
}

// ---------------------------------------------------------------------------
// Workspace layout (120 MB peak, lifetime-overlaid):
//   [0,32M)     Wt region: wqkv_t(24M)/wo_t(8M)/wg_t(32M)/wu_t(32M)/wd_t(32M)
//   [32,56M)    qkv(24M)          -> later gate(32M) spans [32,64M)
//   [56,64M)    attnb(8M)
//   [64,80M)    x1 fp32(16M)
//   [80,88M)    nbuf/n2(8M)
//   [88,118M)   Qh/Kh/Vh(3x~10M)  -> later hbuf(32M) spans [88,120M)
// ---------------------------------------------------------------------------
extern "C" void kernel_launch(void* const* d_in, const int* in_sizes, int n_in,
                              void* d_out, int out_size, void* d_ws, size_t ws_size,
                              hipStream_t stream)
{
    const float* x   = (const float*)d_in[0];
    const float* ans = (const float*)d_in[1];
    const float* wq  = (const float*)d_in[2];
    const float* wk  = (const float*)d_in[3];
    const float* wv  = (const float*)d_in[4];
    const float* wo  = (const float*)d_in[5];
    const float* fns = (const float*)d_in[6];
    const float* wg  = (const float*)d_in[7];
    const float* wu  = (const float*)d_in[8];
    const float* wd  = (const float*)d_in[9];
    (void)in_sizes; (void)n_in; (void)out_size; (void)ws_size;

    char* ws = (char*)d_ws;
    const size_t MB = 1024 * 1024;
    bf16_t* wt_reg = (bf16_t*)(ws);             // 32 MB weight region
    bf16_t* qkv    = (bf16_t*)(ws + 32 * MB);   // 24 MB
    bf16_t* attnb  = (bf16_t*)(ws + 56 * MB);   // 8 MB
    bf16_t* gate   = (bf16_t*)(ws + 32 * MB);   // 32 MB (overlays dead qkv+attnb)
    float*  x1     = (float* )(ws + 64 * MB);   // 16 MB
    bf16_t* nbuf   = (bf16_t*)(ws + 80 * MB);   // 8 MB (also n2)
    bf16_t* Qh     = (bf16_t*)(ws + 88 * MB);   // 8.4 MB
    bf16_t* Kh     = (bf16_t*)(ws + 98 * MB);   // 8.4 MB
    bf16_t* Vh     = (bf16_t*)(ws + 108 * MB);  // 8.4 MB
    bf16_t* hbuf   = (bf16_t*)(ws + 88 * MB);   // 32 MB (overlays dead Qh/Kh/Vh)

    // ---- attention phase ----
    transpose_cvt<<<dim3(64, 64), 256, 0, stream>>>(wq, wt_reg,                             EMBED, EMBED);
    transpose_cvt<<<dim3(64, 64), 256, 0, stream>>>(wk, wt_reg + (size_t)EMBED * EMBED,     EMBED, EMBED);
    transpose_cvt<<<dim3(64, 64), 256, 0, stream>>>(wv, wt_reg + (size_t)2 * EMBED * EMBED, EMBED, EMBED);
    rmsnorm_bf16<<<NTOK, 256, 0, stream>>>(x, ans, nbuf);
    gemm_bt<0><<<dim3(16, 48), 256, 0, stream>>>(nbuf, wt_reg, qkv, nullptr, nullptr, NTOK, QKV_N, EMBED);
    rope_transpose<<<256, 256, 0, stream>>>(qkv, Qh, Kh, Vh);
    attn_sparse<<<dim3(16, 32, 2), 256, 0, stream>>>(Qh, Kh, Vh, attnb);
    transpose_cvt<<<dim3(64, 64), 256, 0, stream>>>(wo, wt_reg, EMBED, EMBED);   // wqkv_t dead
    gemm_bt<1><<<dim3(16, 16), 256, 0, stream>>>(attnb, wt_reg, x1, x, nullptr, NTOK, EMBED, EMBED);

    // ---- MLP phase ----
    rmsnorm_bf16<<<NTOK, 256, 0, stream>>>(x1, fns, nbuf);                       // n2
    transpose_cvt<<<dim3(256, 64), 256, 0, stream>>>(wg, wt_reg, EMBED, MLP);    // wo_t dead
    gemm_bt<0><<<dim3(16, 64), 256, 0, stream>>>(nbuf, wt_reg, gate, nullptr, nullptr, NTOK, MLP, EMBED);
    transpose_cvt<<<dim3(256, 64), 256, 0, stream>>>(wu, wt_reg, EMBED, MLP);    // wg_t dead
    gemm_bt<2><<<dim3(16, 64), 256, 0, stream>>>(nbuf, wt_reg, hbuf, nullptr, gate, NTOK, MLP, EMBED);
    transpose_cvt<<<dim3(64, 256), 256, 0, stream>>>(wd, wt_reg, MLP, EMBED);    // wu_t dead
    gemm_bt<1><<<dim3(16, 16), 256, 0, stream>>>(hbuf, wt_reg, (float*)d_out, x1, nullptr, NTOK, EMBED, MLP);
}

// Round 5
// 984.961 us; speedup vs baseline: 1.5198x; 1.1680x over previous
//
#include <hip/hip_runtime.h>
#include <math.h>

typedef __bf16 bf16_t;
typedef bf16_t bf16x8 __attribute__((ext_vector_type(8)));
typedef bf16_t bf16x2 __attribute__((ext_vector_type(2)));
typedef float f32x4 __attribute__((ext_vector_type(4)));

#define EMBED 2048
#define NHEADS 32
#define HDIM 64
#define MLP 8192
#define SEQ 1024
#define NTOK 2048      // B*S
#define QKV_N 6144

// async global->LDS, 16B per lane; LDS dest = wave-uniform base + lane*16
__device__ __forceinline__ void async_copy16(void* lds, const void* g) {
    __builtin_amdgcn_global_load_lds(
        (const __attribute__((address_space(1))) unsigned int*)g,
        (__attribute__((address_space(3))) unsigned int*)lds, 16, 0, 0);
}

// ---- DPP 16-lane (row) reductions: pure VALU, no LDS pipe ----
template<int CTRL>
__device__ __forceinline__ float dpp_f(float x) {
    return __int_as_float(__builtin_amdgcn_update_dpp(
        __float_as_int(x), __float_as_int(x), CTRL, 0xF, 0xF, false));
}
// row_ror:N = 0x120+N ; rotation folding gives ALL 16 lanes the result
__device__ __forceinline__ float rowmax16(float v) {
    v = fmaxf(v, dpp_f<0x121>(v));
    v = fmaxf(v, dpp_f<0x122>(v));
    v = fmaxf(v, dpp_f<0x124>(v));
    v = fmaxf(v, dpp_f<0x128>(v));
    return v;
}
__device__ __forceinline__ float rowsum16(float v) {
    v += dpp_f<0x121>(v);
    v += dpp_f<0x122>(v);
    v += dpp_f<0x124>(v);
    v += dpp_f<0x128>(v);
    return v;
}

// ---------------------------------------------------------------------------
// C = A(MxK,bf16) @ Bt(NxK,bf16)^T
// EPI=0: bf16 store | EPI=1: fp32 store acc+Res | EPI=2: bf16 silu(Aux)*acc
// 128x128 tile, BK=32, 4 waves, 16x16x32 bf16 MFMA (m97 structure)
// ---------------------------------------------------------------------------
template<int EPI>
__global__ __launch_bounds__(256) void gemm_bt(
    const bf16_t* __restrict__ A, const bf16_t* __restrict__ Bt,
    void* __restrict__ Cout, const float* __restrict__ Res,
    const bf16_t* __restrict__ Aux,
    int M, int N, int K)
{
    __shared__ __align__(16) bf16_t As[128 * 32];
    __shared__ __align__(16) bf16_t Bs[128 * 32];
    const int tid = threadIdx.x;
    const int wave = tid >> 6, lane = tid & 63;
    const int quad = lane >> 4, l15 = lane & 15;
    const int wr = wave >> 1, wc = wave & 1;
    const int m0 = blockIdx.x * 128, n0 = blockIdx.y * 128;
    const int srow = lane >> 2;
    const int scol = (lane & 3) * 8;

    f32x4 acc[4][4] = {};

    for (int k0 = 0; k0 < K; k0 += 32) {
        if (k0) __syncthreads();
#pragma unroll
        for (int s = 0; s < 2; ++s) {
            const int chunk = wave * 2 + s;
            const int row = chunk * 16 + srow;
            async_copy16((char*)As + chunk * 1024,
                         A + (size_t)(m0 + row) * K + k0 + scol);
            async_copy16((char*)Bs + chunk * 1024,
                         Bt + (size_t)(n0 + row) * K + k0 + scol);
        }
        asm volatile("s_waitcnt vmcnt(0)" ::: "memory");
        __syncthreads();

        bf16x8 af[4], bfr[4];
#pragma unroll
        for (int i = 0; i < 4; ++i) {
            af[i]  = *(const bf16x8*)((const char*)As + (wr * 64 + i * 16 + l15) * 64 + quad * 16);
            bfr[i] = *(const bf16x8*)((const char*)Bs + (wc * 64 + i * 16 + l15) * 64 + quad * 16);
        }
#pragma unroll
        for (int i = 0; i < 4; ++i)
#pragma unroll
            for (int j = 0; j < 4; ++j)
                acc[i][j] = __builtin_amdgcn_mfma_f32_16x16x32_bf16(af[i], bfr[j], acc[i][j], 0, 0, 0);
    }

#pragma unroll
    for (int i = 0; i < 4; ++i) {
#pragma unroll
        for (int j = 0; j < 4; ++j) {
#pragma unroll
            for (int r = 0; r < 4; ++r) {
                const int row = m0 + wr * 64 + i * 16 + quad * 4 + r;
                const int col = n0 + wc * 64 + j * 16 + l15;
                const size_t idx = (size_t)row * N + col;
                if (EPI == 0) {
                    ((bf16_t*)Cout)[idx] = (bf16_t)acc[i][j][r];
                } else if (EPI == 1) {
                    ((float*)Cout)[idx] = Res[idx] + acc[i][j][r];
                } else {
                    const float g = (float)Aux[idx];
                    const float s = g / (1.0f + __expf(-g));
                    ((bf16_t*)Cout)[idx] = (bf16_t)(s * acc[i][j][r]);
                }
            }
        }
    }
}

// ---------------------------------------------------------------------------
// W (KxN fp32) -> Wt (NxK bf16), 32x32 LDS tiles
// ---------------------------------------------------------------------------
__global__ __launch_bounds__(256) void transpose_cvt(
    const float* __restrict__ src, bf16_t* __restrict__ dst, int K, int N)
{
    __shared__ float tile[32][33];
    const int tx = threadIdx.x & 31, ty = threadIdx.x >> 5;
    const int n0 = blockIdx.x * 32, k0 = blockIdx.y * 32;
#pragma unroll
    for (int i = 0; i < 4; ++i)
        tile[ty + 8 * i][tx] = src[(size_t)(k0 + ty + 8 * i) * N + n0 + tx];
    __syncthreads();
#pragma unroll
    for (int i = 0; i < 4; ++i)
        dst[(size_t)(n0 + ty + 8 * i) * K + k0 + tx] = (bf16_t)tile[tx][ty + 8 * i];
}

// ---------------------------------------------------------------------------
// RMSNorm: fp32 row (2048) -> bf16 row
// ---------------------------------------------------------------------------
__global__ __launch_bounds__(256) void rmsnorm_bf16(
    const float* __restrict__ x, const float* __restrict__ g, bf16_t* __restrict__ out)
{
    const int row = blockIdx.x;
    const int tid = threadIdx.x;
    const float* xr = x + (size_t)row * EMBED + tid * 8;
    const float4 a = *(const float4*)xr;
    const float4 b = *(const float4*)(xr + 4);
    float ss = a.x * a.x + a.y * a.y + a.z * a.z + a.w * a.w
             + b.x * b.x + b.y * b.y + b.z * b.z + b.w * b.w;
#pragma unroll
    for (int off = 1; off < 64; off <<= 1) ss += __shfl_xor(ss, off);
    __shared__ float red[4];
    if ((tid & 63) == 0) red[tid >> 6] = ss;
    __syncthreads();
    const float rs = rsqrtf((red[0] + red[1] + red[2] + red[3]) * (1.0f / EMBED) + 1e-5f);
    const float* gr = g + tid * 8;
    const float xv[8] = {a.x, a.y, a.z, a.w, b.x, b.y, b.z, b.w};
    bf16x8 o;
#pragma unroll
    for (int e = 0; e < 8; ++e) o[e] = (bf16_t)(xv[e] * rs * gr[e]);
    *(bf16x8*)(out + (size_t)row * EMBED + tid * 8) = o;
}

// ---------------------------------------------------------------------------
// qkv [tok][6144] -> head-major Qh,Kh [(b*32+h)][s][64], RoPE.
// Q additionally scaled by 0.125 (exact) so attention skips the scale.
// ---------------------------------------------------------------------------
__global__ __launch_bounds__(256) void rope_transpose(
    const bf16_t* __restrict__ qkv, bf16_t* __restrict__ Qh, bf16_t* __restrict__ Kh)
{
    const int id = blockIdx.x * 256 + threadIdx.x;   // 0..65535
    const int tok = id >> 5;
    const int h = id & 31;
    const int s = tok & (SEQ - 1);
    const int bh = (tok >> 10) * NHEADS + h;
    const size_t dst = ((size_t)bh * SEQ + s) * HDIM;

    const bf16_t* q = qkv + (size_t)tok * QKV_N + h * HDIM;
    const bf16_t* k = q + EMBED;

    const bf16x2* qp = (const bf16x2*)q;
    const bf16x2* kp = (const bf16x2*)k;
    bf16x2* qo = (bf16x2*)(Qh + dst);
    bf16x2* ko = (bf16x2*)(Kh + dst);
    for (int i = 0; i < 32; ++i) {
        // 1/theta^(i/32) = exp2(-i*log2(5e5)/32)
        const float inv = exp2f((float)i * -0.59161151779f);
        const float ang = (float)s * inv;
        float sn, cs;
        sincosf(ang, &sn, &cs);
        bf16x2 qv = qp[i], kv = kp[i];
        const float q0 = (float)qv[0], q1 = (float)qv[1];
        const float k0 = (float)kv[0], k1 = (float)kv[1];
        qv[0] = (bf16_t)((q0 * cs - q1 * sn) * 0.125f);
        qv[1] = (bf16_t)((q0 * sn + q1 * cs) * 0.125f);
        kv[0] = (bf16_t)(k0 * cs - k1 * sn);
        kv[1] = (bf16_t)(k0 * sn + k1 * cs);
        qo[i] = qv; ko[i] = kv;
    }
}

// ---------------------------------------------------------------------------
// V transpose: qkv v-section -> Vt[(b*32+h)][dim][seq]
// grid (32 s-tiles, 64 bh), 256 threads
// ---------------------------------------------------------------------------
__global__ __launch_bounds__(256) void transpose_v(
    const bf16_t* __restrict__ qkv, bf16_t* __restrict__ Vt)
{
    __shared__ bf16_t tile[32][66];
    const int st = blockIdx.x;       // seq tile (32 rows)
    const int bh = blockIdx.y;
    const int b = bh >> 5, h = bh & 31;
    const int tid = threadIdx.x;

    const int d = tid & 63, sr = tid >> 6;
    const bf16_t* src = qkv + (size_t)(b * SEQ + st * 32) * QKV_N + 2 * EMBED + h * HDIM;
#pragma unroll
    for (int i = 0; i < 8; ++i) {
        const int s = i * 4 + sr;
        tile[s][d] = src[(size_t)s * QKV_N + d];
    }
    __syncthreads();
    const int s2 = tid & 31, dr = tid >> 5;
    bf16_t* dstp = Vt + (size_t)bh * HDIM * SEQ + st * 32;
#pragma unroll
    for (int i = 0; i < 8; ++i) {
        const int dd = i * 8 + dr;
        dstp[(size_t)dd * SEQ + s2] = tile[s2][dd];
    }
}

// ---------------------------------------------------------------------------
// Tile-sparse attention v4. Block=(qg,h,b), 4 waves; wave owns qt=wave*16+qg
// (balanced). DPP row reductions (no LDS shuffles). PV B-frags direct from
// global V^T. P transposed C->A layout via small LDS buffer.
// ---------------------------------------------------------------------------
__global__ __launch_bounds__(256, 4) void attn_sparse(
    const bf16_t* __restrict__ Qh, const bf16_t* __restrict__ Kh,
    const bf16_t* __restrict__ Vt, bf16_t* __restrict__ attn)
{
    const int qg = blockIdx.x;       // 0..15
    const int h  = blockIdx.y;
    const int b  = blockIdx.z;
    const int tid  = threadIdx.x;
    const int wave = tid >> 6, lane = tid & 63;
    const int quad = lane >> 4, l15 = lane & 15;
    const int qt = wave * 16 + qg;   // 0..63, block work sum ~constant

    __shared__ __align__(16) float  tilemax[4][16][68];
    __shared__ __align__(16) bf16_t Plds[4][16][40];
    __shared__ unsigned long long qmask[4][16];

    const size_t hoff = (size_t)(b * NHEADS + h) * SEQ * HDIM;
    const bf16_t* Qb  = Qh + hoff;
    const bf16_t* Kb  = Kh + hoff;
    const bf16_t* Vtb = Vt + hoff;   // [64][1024]

    const bf16_t* qrow = Qb + (size_t)(qt * 16 + l15) * HDIM;
    const bf16x8 qf0 = *(const bf16x8*)(qrow + quad * 8);
    const bf16x8 qf1 = *(const bf16x8*)(qrow + 32 + quad * 8);

    // ---- pass 1: tile maxima (DPP reduce, 1-ahead prefetch) ----
    const bf16_t* kbase = Kb + (size_t)l15 * HDIM + quad * 8;
    bf16x8 kc0 = *(const bf16x8*)(kbase);
    bf16x8 kc1 = *(const bf16x8*)(kbase + 32);
    for (int t = 0; t <= qt; ++t) {
        const bf16_t* knp = kbase + (size_t)((t < qt) ? t + 1 : t) * (16 * HDIM);
        const bf16x8 kn0 = *(const bf16x8*)(knp);
        const bf16x8 kn1 = *(const bf16x8*)(knp + 32);
        f32x4 sc = {0.f, 0.f, 0.f, 0.f};
        sc = __builtin_amdgcn_mfma_f32_16x16x32_bf16(qf0, kc0, sc, 0, 0, 0);
        sc = __builtin_amdgcn_mfma_f32_16x16x32_bf16(qf1, kc1, sc, 0, 0, 0);
#pragma unroll
        for (int r = 0; r < 4; ++r) {
            const int qr = quad * 4 + r;
            float v = (t == qt && l15 > qr) ? -3.0e38f : sc[r];
            v = rowmax16(v);
            if (l15 == 0) tilemax[wave][qr][t] = v;
        }
        kc0 = kn0; kc1 = kn1;
    }
    asm volatile("s_waitcnt lgkmcnt(0)" ::: "memory");   // in-wave DS drain

    // ---- selection: top-12 (strict >, earliest on ties) + own ----
    if (lane < 16) {
        unsigned long long m = 0;
        const int cnt = qt + 1;
        if (cnt <= 12) {
            m = (1ull << cnt) - 1ull;
        } else {
            const float* tmrow = &tilemax[wave][lane][0];
            const int c4 = qt >> 2;
            for (int it = 0; it < 12; ++it) {
                float best = -3.9e38f; int bi = 0;
                for (int c = 0; c <= c4; ++c) {
                    const float4 v4 = *(const float4*)(tmrow + c * 4);
                    const int tb = c * 4;
                    if (tb + 0 <= qt && !((m >> (tb + 0)) & 1ull) && v4.x > best) { best = v4.x; bi = tb + 0; }
                    if (tb + 1 <= qt && !((m >> (tb + 1)) & 1ull) && v4.y > best) { best = v4.y; bi = tb + 1; }
                    if (tb + 2 <= qt && !((m >> (tb + 2)) & 1ull) && v4.z > best) { best = v4.z; bi = tb + 2; }
                    if (tb + 3 <= qt && !((m >> (tb + 3)) & 1ull) && v4.w > best) { best = v4.w; bi = tb + 3; }
                }
                m |= 1ull << bi;
            }
        }
        m |= 1ull << qt;
        qmask[wave][lane] = m;
    }
    asm volatile("s_waitcnt lgkmcnt(0)" ::: "memory");

    unsigned long long un = 0;
#pragma unroll
    for (int i = 0; i < 16; ++i) un |= qmask[wave][i];
    unsigned long long myrow[4];
#pragma unroll
    for (int r = 0; r < 4; ++r) myrow[r] = qmask[wave][quad * 4 + r];

    float m_run[4], l_run[4];
#pragma unroll
    for (int r = 0; r < 4; ++r) { m_run[r] = -3.0e38f; l_run[r] = 0.f; }
    f32x4 o[4] = {};   // o[jb][r] = D[quad*4+r][jb*16+l15]

    // ---- pass 2: selected tiles in pairs, MFMA PV ----
    unsigned long long sel = un;
    while (sel) {
        const int t0 = (int)__builtin_ctzll(sel); sel &= sel - 1ull;
        int t1 = -1;
        if (sel) { t1 = (int)__builtin_ctzll(sel); sel &= sel - 1ull; }
        const int t1e = (t1 >= 0) ? t1 : t0;

        const bf16_t* kr0 = Kb + (size_t)(t0 * 16 + l15) * HDIM + quad * 8;
        const bf16x8 k00 = *(const bf16x8*)(kr0);
        const bf16x8 k01 = *(const bf16x8*)(kr0 + 32);
        const bf16_t* kr1 = Kb + (size_t)(t1e * 16 + l15) * HDIM + quad * 8;
        const bf16x8 k10 = *(const bf16x8*)(kr1);
        const bf16x8 k11 = *(const bf16x8*)(kr1 + 32);

        // B-frags from global V^T (keys: quad<2 -> t0, quad>=2 -> t1e)
        const int colb = ((quad < 2) ? t0 : t1e) * 16 + (quad & 1) * 8;
        bf16x8 vf[4];
#pragma unroll
        for (int jb = 0; jb < 4; ++jb)
            vf[jb] = *(const bf16x8*)(Vtb + (size_t)(jb * 16 + l15) * SEQ + colb);

        f32x4 s0 = {0.f, 0.f, 0.f, 0.f}, s1 = {0.f, 0.f, 0.f, 0.f};
        s0 = __builtin_amdgcn_mfma_f32_16x16x32_bf16(qf0, k00, s0, 0, 0, 0);
        s0 = __builtin_amdgcn_mfma_f32_16x16x32_bf16(qf1, k01, s0, 0, 0, 0);
        s1 = __builtin_amdgcn_mfma_f32_16x16x32_bf16(qf0, k10, s1, 0, 0, 0);
        s1 = __builtin_amdgcn_mfma_f32_16x16x32_bf16(qf1, k11, s1, 0, 0, 0);

#pragma unroll
        for (int r = 0; r < 4; ++r) {
            const int qr = quad * 4 + r;
            const bool ok0 = ((myrow[r] >> t0) & 1ull) && (t0 < qt || l15 <= qr);
            const bool ok1 = (t1 >= 0) && ((myrow[r] >> t1) & 1ull) && (t1 < qt || l15 <= qr);
            const float sv0 = ok0 ? s0[r] : -3.0e38f;
            const float sv1 = ok1 ? s1[r] : -3.0e38f;
            const float mt = rowmax16(fmaxf(sv0, sv1));
            const float mn = fmaxf(m_run[r], mt);
            const float al = __expf(m_run[r] - mn);
            const float p0 = ok0 ? __expf(sv0 - mn) : 0.f;
            const float p1 = ok1 ? __expf(sv1 - mn) : 0.f;
            const float rsum = rowsum16(p0 + p1);
            l_run[r] = l_run[r] * al + rsum;
            m_run[r] = mn;
            Plds[wave][qr][l15]      = (bf16_t)p0;
            Plds[wave][qr][16 + l15] = (bf16_t)p1;
#pragma unroll
            for (int jb = 0; jb < 4; ++jb) o[jb][r] *= al;
        }
        asm volatile("s_waitcnt lgkmcnt(0)" ::: "memory");

        const bf16x8 pa = *(const bf16x8*)&Plds[wave][l15][quad * 8];
#pragma unroll
        for (int jb = 0; jb < 4; ++jb)
            o[jb] = __builtin_amdgcn_mfma_f32_16x16x32_bf16(pa, vf[jb], o[jb], 0, 0, 0);
    }

    // ---- epilogue: normalize, store ----
    const int tok0 = b * SEQ + qt * 16;
#pragma unroll
    for (int r = 0; r < 4; ++r) {
        const int qr = quad * 4 + r;
        const float inv = 1.0f / l_run[r];
        bf16_t* op = attn + (size_t)(tok0 + qr) * EMBED + h * HDIM + l15;
#pragma unroll
        for (int jb = 0; jb < 4; ++jb)
            op[jb * 16] = (bf16_t)(o[jb][r] * inv);
    }
}

// ---------------------------------------------------------------------------
// Workspace layout (120 MB peak, lifetime-overlaid):
//   [0,32M)     Wt region: wqkv_t(24M)/wo_t(8M)/wg_t(32M)/wu_t(32M)/wd_t(32M)
//   [32,56M)    qkv(24M)          -> later gate(32M) spans [32,64M)
//   [56,64M)    attnb(8M)
//   [64,80M)    x1 fp32(16M)
//   [80,88M)    nbuf/n2(8M)
//   [88,118M)   Qh/Kh/Vt(3x~10M)  -> later hbuf(32M) spans [88,120M)
// ---------------------------------------------------------------------------
extern "C" void kernel_launch(void* const* d_in, const int* in_sizes, int n_in,
                              void* d_out, int out_size, void* d_ws, size_t ws_size,
                              hipStream_t stream)
{
    const float* x   = (const float*)d_in[0];
    const float* ans = (const float*)d_in[1];
    const float* wq  = (const float*)d_in[2];
    const float* wk  = (const float*)d_in[3];
    const float* wv  = (const float*)d_in[4];
    const float* wo  = (const float*)d_in[5];
    const float* fns = (const float*)d_in[6];
    const float* wg  = (const float*)d_in[7];
    const float* wu  = (const float*)d_in[8];
    const float* wd  = (const float*)d_in[9];
    (void)in_sizes; (void)n_in; (void)out_size; (void)ws_size;

    char* ws = (char*)d_ws;
    const size_t MB = 1024 * 1024;
    bf16_t* wt_reg = (bf16_t*)(ws);             // 32 MB weight region
    bf16_t* qkv    = (bf16_t*)(ws + 32 * MB);   // 24 MB
    bf16_t* attnb  = (bf16_t*)(ws + 56 * MB);   // 8 MB
    bf16_t* gate   = (bf16_t*)(ws + 32 * MB);   // 32 MB (overlays dead qkv+attnb)
    float*  x1     = (float* )(ws + 64 * MB);   // 16 MB
    bf16_t* nbuf   = (bf16_t*)(ws + 80 * MB);   // 8 MB (also n2)
    bf16_t* Qh     = (bf16_t*)(ws + 88 * MB);   // 8.4 MB
    bf16_t* Kh     = (bf16_t*)(ws + 98 * MB);   // 8.4 MB
    bf16_t* Vt     = (bf16_t*)(ws + 108 * MB);  // 8.4 MB (transposed V)
    bf16_t* hbuf   = (bf16_t*)(ws + 88 * MB);   // 32 MB (overlays dead Qh/Kh/Vt)

    // ---- attention phase ----
    transpose_cvt<<<dim3(64, 64), 256, 0, stream>>>(wq, wt_reg,                             EMBED, EMBED);
    transpose_cvt<<<dim3(64, 64), 256, 0, stream>>>(wk, wt_reg + (size_t)EMBED * EMBED,     EMBED, EMBED);
    transpose_cvt<<<dim3(64, 64), 256, 0, stream>>>(wv, wt_reg + (size_t)2 * EMBED * EMBED, EMBED, EMBED);
    rmsnorm_bf16<<<NTOK, 256, 0, stream>>>(x, ans, nbuf);
    gemm_bt<0><<<dim3(16, 48), 256, 0, stream>>>(nbuf, wt_reg, qkv, nullptr, nullptr, NTOK, QKV_N, EMBED);
    rope_transpose<<<256, 256, 0, stream>>>(qkv, Qh, Kh);
    transpose_v<<<dim3(32, 64), 256, 0, stream>>>(qkv, Vt);
    attn_sparse<<<dim3(16, 32, 2), 256, 0, stream>>>(Qh, Kh, Vt, attnb);
    transpose_cvt<<<dim3(64, 64), 256, 0, stream>>>(wo, wt_reg, EMBED, EMBED);   // wqkv_t dead
    gemm_bt<1><<<dim3(16, 16), 256, 0, stream>>>(attnb, wt_reg, x1, x, nullptr, NTOK, EMBED, EMBED);

    // ---- MLP phase ----
    rmsnorm_bf16<<<NTOK, 256, 0, stream>>>(x1, fns, nbuf);                       // n2
    transpose_cvt<<<dim3(256, 64), 256, 0, stream>>>(wg, wt_reg, EMBED, MLP);    // wo_t dead
    gemm_bt<0><<<dim3(16, 64), 256, 0, stream>>>(nbuf, wt_reg, gate, nullptr, nullptr, NTOK, MLP, EMBED);
    transpose_cvt<<<dim3(256, 64), 256, 0, stream>>>(wu, wt_reg, EMBED, MLP);    // wg_t dead
    gemm_bt<2><<<dim3(16, 64), 256, 0, stream>>>(nbuf, wt_reg, hbuf, nullptr, gate, NTOK, MLP, EMBED);
    transpose_cvt<<<dim3(64, 256), 256, 0, stream>>>(wd, wt_reg, MLP, EMBED);    // wu_t dead
    gemm_bt<1><<<dim3(16, 16), 256, 0, stream>>>(hbuf, wt_reg, (float*)d_out, x1, nullptr, NTOK, EMBED, MLP);
}